// Round 1
// baseline (332.460 us; speedup 1.0000x reference)
//
#include <hip/hip_runtime.h>
#include <hip/hip_bf16.h>

// GraphSAGE 3-layer, MI355X. Key restructuring: aggregate AFTER projection
// (mean-agg is linear, commutes with matmul + degree division), so the
// 4096-dim edge gather (1.3 GB) becomes a 512-dim gather (160 MB).
// Layers 1/2: C = A @ [Wl;Wr]^T via bf16 MFMA 128x128-tile GEMM (m97 structure),
// then CSR mean-aggregate cols 0..511, combine with cols 512..1023 + bias + relu.
// Layer 3: project to 12 cols (y3|z3) with a small vector GEMM, aggregate in 6-dim.

#define N_NODES 10000
#define N_EDGES 80000
#define F_DIM   4096
#define H_DIM   512
#define C_DIM   6
#define MP      10112   // 79 * 128, M padded for the GEMM tiling

typedef __attribute__((ext_vector_type(4))) float f32x4;
typedef __attribute__((ext_vector_type(8))) short bf16x8;

__device__ __forceinline__ unsigned short f2bf(float f) {
  unsigned int u = __float_as_uint(f);
  u += 0x7FFFu + ((u >> 16) & 1u);   // round-to-nearest-even
  return (unsigned short)(u >> 16);
}

__device__ __forceinline__ void gload16(const short* g, short* l) {
  __builtin_amdgcn_global_load_lds(
      (const __attribute__((address_space(1))) unsigned int*)g,
      (__attribute__((address_space(3))) unsigned int*)l, 16, 0, 0);
}

// ---------------- CSR build ----------------
__global__ void zero_ints(int* a, int n) {
  int i = blockIdx.x * 256 + threadIdx.x;
  if (i < n) a[i] = 0;
}

__global__ void count_deg(const int* __restrict__ dst, int* __restrict__ deg, int e) {
  int i = blockIdx.x * 256 + threadIdx.x;
  if (i < e) atomicAdd(&deg[dst[i]], 1);
}

__global__ __launch_bounds__(1024) void scan_deg(const int* __restrict__ deg,
                                                 int* __restrict__ off,
                                                 float* __restrict__ inv_deg, int n) {
  __shared__ int lds[1024];
  __shared__ int carry_s;
  int t = threadIdx.x;
  if (t == 0) carry_s = 0;
  __syncthreads();
  for (int base = 0; base < n; base += 1024) {
    int i = base + t;
    int v = (i < n) ? deg[i] : 0;
    lds[t] = v;
    __syncthreads();
    for (int s = 1; s < 1024; s <<= 1) {
      int add = (t >= s) ? lds[t - s] : 0;
      __syncthreads();
      lds[t] += add;
      __syncthreads();
    }
    int incl = lds[t];
    int c = carry_s;
    if (i < n) {
      off[i + 1] = c + incl;
      inv_deg[i] = 1.0f / fmaxf((float)v, 1.0f);
    }
    __syncthreads();
    if (t == 1023) carry_s = c + incl;
    __syncthreads();
  }
  if (t == 0) off[0] = 0;
}

__global__ void fill_csr(const int* __restrict__ src, const int* __restrict__ dst,
                         const int* __restrict__ off, int* __restrict__ cur,
                         int* __restrict__ csr, int e) {
  int i = blockIdx.x * 256 + threadIdx.x;
  if (i < e) {
    int d = dst[i];
    int p = atomicAdd(&cur[d], 1);
    csr[off[d] + p] = src[i];
  }
}

// ---------------- dtype conversion ----------------
// f32 -> bf16, 8 elems/thread; zero-fills the padded tail (idx >= nvalid).
__global__ void cvt_bf16(const float* __restrict__ s, short* __restrict__ d,
                         long nvalid, long ntotal) {
  long idx = ((long)blockIdx.x * 256 + threadIdx.x) * 8;
  if (idx >= ntotal) return;
  unsigned short o[8];
  if (idx < nvalid) {
    f32x4 a = *(const f32x4*)&s[idx];
    f32x4 b = *(const f32x4*)&s[idx + 4];
    o[0] = f2bf(a[0]); o[1] = f2bf(a[1]); o[2] = f2bf(a[2]); o[3] = f2bf(a[3]);
    o[4] = f2bf(b[0]); o[5] = f2bf(b[1]); o[6] = f2bf(b[2]); o[7] = f2bf(b[3]);
  } else {
    for (int j = 0; j < 8; ++j) o[j] = 0;
  }
  *(bf16x8*)&d[idx] = *(bf16x8*)o;
}

// [Wl(512xK); Wr(512xK)] -> bf16 [1024][K], flat-contiguous so flat index works.
__global__ void cvt_wcat(const float* __restrict__ wl, const float* __restrict__ wr,
                         short* __restrict__ d, long half) {
  long idx = ((long)blockIdx.x * 256 + threadIdx.x) * 8;
  if (idx >= 2 * half) return;
  const float* s = (idx < half) ? (wl + idx) : (wr + (idx - half));
  f32x4 a = *(const f32x4*)s;
  f32x4 b = *(const f32x4*)(s + 4);
  unsigned short o[8];
  o[0] = f2bf(a[0]); o[1] = f2bf(a[1]); o[2] = f2bf(a[2]); o[3] = f2bf(a[3]);
  o[4] = f2bf(b[0]); o[5] = f2bf(b[1]); o[6] = f2bf(b[2]); o[7] = f2bf(b[3]);
  *(bf16x8*)&d[idx] = *(bf16x8*)o;
}

// ---------------- bf16 MFMA GEMM: C[M][Nt] = A[M][K] @ B[Nt][K]^T ----------------
// 128x128 tile, 4 waves (2x2 of 64x64), 16x16x32 MFMA, global_load_lds width 16.
__global__ __launch_bounds__(256, 2) void gemm_bt(
    const short* __restrict__ A, const short* __restrict__ B,
    float* __restrict__ C, int M, int Nt, int K) {
  __shared__ short lds[2 * 128 * 32];           // A: [0,4096) shorts, B: [4096,8192)
  const int tiles_n = Nt >> 7;
  const int bm = blockIdx.x / tiles_n;
  const int bn = blockIdx.x % tiles_n;
  const int t = threadIdx.x;
  const int lane = t & 63;
  const int w = t >> 6;
  const int wr = w >> 1, wc = w & 1;
  const int lr = lane & 15, lk = lane >> 4;

  f32x4 acc[4][4] = {};

  const int arow = t >> 2, acol = (t & 3) * 8;  // staging: thread t -> LDS bytes [16t,16t+16)
  const size_t Abase = (size_t)(bm * 128 + arow) * K + acol;
  const size_t Bbase = (size_t)(bn * 128 + arow) * K + acol;
  short* ldsA = lds;
  short* ldsB = lds + 4096;
  short* dA0 = ldsA + t * 8;
  short* dA1 = ldsA + 2048 + t * 8;
  short* dB0 = ldsB + t * 8;
  short* dB1 = ldsB + 2048 + t * 8;

  for (int k0 = 0; k0 < K; k0 += 32) {
    __syncthreads();
    gload16(A + Abase + k0, dA0);
    gload16(A + Abase + (size_t)64 * K + k0, dA1);
    gload16(B + Bbase + k0, dB0);
    gload16(B + Bbase + (size_t)64 * K + k0, dB1);
    __syncthreads();
    bf16x8 a[4], b[4];
#pragma unroll
    for (int m = 0; m < 4; ++m)
      a[m] = *(bf16x8*)&ldsA[(wr * 64 + m * 16 + lr) * 32 + lk * 8];
#pragma unroll
    for (int n = 0; n < 4; ++n)
      b[n] = *(bf16x8*)&ldsB[(wc * 64 + n * 16 + lr) * 32 + lk * 8];
#pragma unroll
    for (int m = 0; m < 4; ++m)
#pragma unroll
      for (int n = 0; n < 4; ++n)
        acc[m][n] = __builtin_amdgcn_mfma_f32_16x16x32_bf16(a[m], b[n], acc[m][n], 0, 0, 0);
  }

  const int crow0 = bm * 128 + wr * 64 + lk * 4;   // C/D: col=lane&15, row=(lane>>4)*4+j
  const int ccol0 = bn * 128 + wc * 64 + lr;
#pragma unroll
  for (int m = 0; m < 4; ++m)
#pragma unroll
    for (int n = 0; n < 4; ++n)
#pragma unroll
      for (int j = 0; j < 4; ++j)
        C[(size_t)(crow0 + m * 16 + j) * Nt + ccol0 + n * 16] = acc[m][n][j];
}

// ---------------- CSR mean-aggregate (512 cols of a [*,1024] matrix) ----------------
__global__ __launch_bounds__(128) void aggregate_k(
    const float* __restrict__ Y, const int* __restrict__ off, const int* __restrict__ csr,
    const float* __restrict__ inv_deg, float* __restrict__ agg) {
  int i = blockIdx.x;
  int t = threadIdx.x;             // t in [0,128): one float4 of the 512 cols
  int e0 = off[i], e1 = off[i + 1];
  float sx = 0.f, sy = 0.f, sz = 0.f, sw = 0.f;
  for (int e = e0; e < e1; ++e) {
    int s = csr[e];
    f32x4 v = ((const f32x4*)Y)[(size_t)s * 256 + t];   // row stride 1024 f32 = 256 f32x4
    sx += v[0]; sy += v[1]; sz += v[2]; sw += v[3];
  }
  float id = inv_deg[i];
  f32x4 r = {sx * id, sy * id, sz * id, sw * id};
  ((f32x4*)agg)[(size_t)i * 128 + t] = r;
}

// ---------------- combine: relu(agg + b + z), write bf16 (and optional f32) ----------------
__global__ void combine_k(const float* __restrict__ agg, const float* __restrict__ Cbuf,
                          const float* __restrict__ bias, short* __restrict__ hb,
                          float* __restrict__ hf, int n) {
  int idx = blockIdx.x * 256 + threadIdx.x;    // float4 granularity over [n][128]
  if (idx >= n * 128) return;
  int i = idx >> 7, tt = idx & 127;
  f32x4 a = ((const f32x4*)agg)[idx];
  f32x4 z = ((const f32x4*)Cbuf)[(size_t)i * 256 + 128 + tt];  // cols 512..1023
  f32x4 b = ((const f32x4*)bias)[tt];
  f32x4 r;
#pragma unroll
  for (int j = 0; j < 4; ++j) r[j] = fmaxf(a[j] + b[j] + z[j], 0.f);
  if (hf) ((f32x4*)hf)[idx] = r;
  unsigned short o[4] = {f2bf(r[0]), f2bf(r[1]), f2bf(r[2]), f2bf(r[3])};
  *(uint2*)&hb[(size_t)i * 512 + tt * 4] = *(uint2*)o;
}

// ---------------- layer 3: [N,512] f32 @ [12,512]^T -> y3z3 [N][12] ----------------
__global__ __launch_bounds__(256) void l3_gemm(const float* __restrict__ h2,
                                               const float* __restrict__ w3l,
                                               const float* __restrict__ w3r,
                                               float* __restrict__ y3z3, int n) {
  __shared__ float wsh[12 * 512];
  int t = threadIdx.x;
  for (int idx = t; idx < 12 * 512; idx += 256) {
    int r = idx >> 9, c = idx & 511;
    wsh[idx] = (r < 6) ? w3l[r * 512 + c] : w3r[(r - 6) * 512 + c];
  }
  __syncthreads();
  int wid = t >> 6, lane = t & 63;
  int row = blockIdx.x * 4 + wid;
  if (row >= n) return;
  const f32x4* h4 = (const f32x4*)(h2 + (size_t)row * 512);
  f32x4 ha = h4[lane * 2], hb = h4[lane * 2 + 1];
#pragma unroll
  for (int c = 0; c < 12; ++c) {
    const f32x4* w4 = (const f32x4*)&wsh[c * 512];
    f32x4 wa = w4[lane * 2], wb = w4[lane * 2 + 1];
    float s = ha[0] * wa[0] + ha[1] * wa[1] + ha[2] * wa[2] + ha[3] * wa[3]
            + hb[0] * wb[0] + hb[1] * wb[1] + hb[2] * wb[2] + hb[3] * wb[3];
#pragma unroll
    for (int o = 32; o; o >>= 1) s += __shfl_down(s, o, 64);
    if (lane == 0) y3z3[(size_t)row * 12 + c] = s;
  }
}

__global__ void final_out(const float* __restrict__ y3z3, const int* __restrict__ off,
                          const int* __restrict__ csr, const float* __restrict__ inv_deg,
                          const float* __restrict__ b3, float* __restrict__ out, int n) {
  int idx = blockIdx.x * 256 + threadIdx.x;
  if (idx >= n * 6) return;
  int i = idx / 6, c = idx - i * 6;
  float s = 0.f;
  int e0 = off[i], e1 = off[i + 1];
  for (int e = e0; e < e1; ++e) s += y3z3[(size_t)csr[e] * 12 + c];
  out[idx] = s * inv_deg[i] + b3[c] + y3z3[(size_t)i * 12 + 6 + c];
}

// ---------------- host ----------------
extern "C" void kernel_launch(void* const* d_in, const int* in_sizes, int n_in,
                              void* d_out, int out_size, void* d_ws, size_t ws_size,
                              hipStream_t stream) {
  const float* x   = (const float*)d_in[0];
  const int*   ei  = (const int*)d_in[1];
  const float* W1l = (const float*)d_in[2];
  const float* b1  = (const float*)d_in[3];
  const float* W1r = (const float*)d_in[4];
  const float* W2l = (const float*)d_in[5];
  const float* b2  = (const float*)d_in[6];
  const float* W2r = (const float*)d_in[7];
  const float* W3l = (const float*)d_in[8];
  const float* b3  = (const float*)d_in[9];
  const float* W3r = (const float*)d_in[10];
  const int* src = ei;
  const int* dst = ei + N_EDGES;

  char* p = (char*)d_ws;
  auto alloc = [&](size_t bytes) { char* r = p; p += (bytes + 255) & ~(size_t)255; return r; };
  int*   deg     = (int*)alloc((size_t)N_NODES * 4);
  int*   off     = (int*)alloc((size_t)(N_NODES + 1) * 4);
  int*   cur     = (int*)alloc((size_t)N_NODES * 4);
  int*   csr     = (int*)alloc((size_t)N_EDGES * 4);
  float* inv_deg = (float*)alloc((size_t)N_NODES * 4);
  short* xb      = (short*)alloc((size_t)MP * F_DIM * 2);
  short* Wc      = (short*)alloc((size_t)1024 * F_DIM * 2);
  float* Cbuf    = (float*)alloc((size_t)MP * 1024 * 4);
  float* agg     = (float*)alloc((size_t)N_NODES * 512 * 4);
  short* hbuf    = (short*)alloc((size_t)MP * 512 * 2);
  float* y3z3    = (float*)alloc((size_t)N_NODES * 12 * 4);

  float* h_out   = (float*)d_out;                       // [N][512]
  float* o_out   = (float*)d_out + (size_t)N_NODES * 512;  // [N][6]

  // CSR build
  zero_ints<<<(N_NODES + 255) / 256, 256, 0, stream>>>(deg, N_NODES);
  zero_ints<<<(N_NODES + 255) / 256, 256, 0, stream>>>(cur, N_NODES);
  count_deg<<<(N_EDGES + 255) / 256, 256, 0, stream>>>(dst, deg, N_EDGES);
  scan_deg<<<1, 1024, 0, stream>>>(deg, off, inv_deg, N_NODES);
  fill_csr<<<(N_EDGES + 255) / 256, 256, 0, stream>>>(src, dst, off, cur, csr, N_EDGES);

  // x -> bf16 (padded rows zeroed)
  {
    long ntotal = (long)MP * F_DIM;
    cvt_bf16<<<(int)((ntotal / 8 + 255) / 256), 256, 0, stream>>>(
        x, xb, (long)N_NODES * F_DIM, ntotal);
  }

  // ---- layer 1 ----
  cvt_wcat<<<(int)(((long)1024 * F_DIM / 8 + 255) / 256), 256, 0, stream>>>(
      W1l, W1r, Wc, (long)512 * F_DIM);
  gemm_bt<<<(MP / 128) * (1024 / 128), 256, 0, stream>>>(xb, Wc, Cbuf, MP, 1024, F_DIM);
  aggregate_k<<<N_NODES, 128, 0, stream>>>(Cbuf, off, csr, inv_deg, agg);
  combine_k<<<(N_NODES * 128 + 255) / 256, 256, 0, stream>>>(agg, Cbuf, b1, hbuf, nullptr, N_NODES);

  // ---- layer 2 ----
  cvt_wcat<<<(int)(((long)1024 * 512 / 8 + 255) / 256), 256, 0, stream>>>(
      W2l, W2r, Wc, (long)512 * 512);
  gemm_bt<<<(MP / 128) * (1024 / 128), 256, 0, stream>>>(hbuf, Wc, Cbuf, MP, 1024, 512);
  aggregate_k<<<N_NODES, 128, 0, stream>>>(Cbuf, off, csr, inv_deg, agg);
  combine_k<<<(N_NODES * 128 + 255) / 256, 256, 0, stream>>>(agg, Cbuf, b2, hbuf, h_out, N_NODES);

  // ---- layer 3 ----
  l3_gemm<<<(N_NODES + 3) / 4, 256, 0, stream>>>(h_out, W3l, W3r, y3z3, N_NODES);
  final_out<<<(N_NODES * 6 + 255) / 256, 256, 0, stream>>>(y3z3, off, csr, inv_deg, b3, o_out, N_NODES);
}

// Round 2
// 306.447 us; speedup vs baseline: 1.0849x; 1.0849x over previous
//
#include <hip/hip_runtime.h>
#include <hip/hip_bf16.h>

// GraphSAGE 3-layer, MI355X. Aggregate AFTER projection (mean-agg commutes
// with matmul), so edge gathers happen in 512-dim, not 4096-dim.
// R2: BK=64 GEMM (half the barriers), shuffle scan, fused aggregate+combine.

#define N_NODES 10000
#define N_EDGES 80000
#define F_DIM   4096
#define H_DIM   512
#define C_DIM   6
#define MP      10112   // 79 * 128, M padded for GEMM tiling

typedef __attribute__((ext_vector_type(4))) float f32x4;
typedef __attribute__((ext_vector_type(8))) short bf16x8;

__device__ __forceinline__ unsigned short f2bf(float f) {
  unsigned int u = __float_as_uint(f);
  u += 0x7FFFu + ((u >> 16) & 1u);   // round-to-nearest-even
  return (unsigned short)(u >> 16);
}

__device__ __forceinline__ void gload16(const short* g, short* l) {
  __builtin_amdgcn_global_load_lds(
      (const __attribute__((address_space(1))) unsigned int*)g,
      (__attribute__((address_space(3))) unsigned int*)l, 16, 0, 0);
}

// ---------------- CSR build ----------------
__global__ void count_deg(const int* __restrict__ dst, int* __restrict__ deg, int e) {
  int i = blockIdx.x * 256 + threadIdx.x;
  if (i < e) atomicAdd(&deg[dst[i]], 1);
}

// Single-block shuffle scan: 1024 threads x CH=10 contiguous elems = 10240 >= N.
__global__ __launch_bounds__(1024) void scan_deg(const int* __restrict__ deg,
                                                 int* __restrict__ off,
                                                 float* __restrict__ inv_deg, int n) {
  __shared__ int wtot[16];
  const int CH = 10;
  int t = threadIdx.x;
  int lane = t & 63, wid = t >> 6;
  int base = t * CH;
  int v[CH];
  int s = 0;
#pragma unroll
  for (int j = 0; j < CH; ++j) {
    int i = base + j;
    v[j] = (i < n) ? deg[i] : 0;
    s += v[j];
  }
  // wave-inclusive scan of per-thread sums
  int incl = s;
#pragma unroll
  for (int o = 1; o < 64; o <<= 1) {
    int u = __shfl_up(incl, o, 64);
    if (lane >= o) incl += u;
  }
  if (lane == 63) wtot[wid] = incl;
  __syncthreads();
  if (wid == 0 && lane < 16) {
    int w = wtot[lane];
    int wi = w;
#pragma unroll
    for (int o = 1; o < 16; o <<= 1) {
      int u = __shfl_up(wi, o, 64);
      if (lane >= o) wi += u;
    }
    wtot[lane] = wi - w;   // exclusive wave offset
  }
  __syncthreads();
  int run = wtot[wid] + incl - s;  // exclusive prefix for this thread's chunk
#pragma unroll
  for (int j = 0; j < CH; ++j) {
    int i = base + j;
    if (i < n) {
      run += v[j];
      off[i + 1] = run;
      inv_deg[i] = 1.0f / fmaxf((float)v[j], 1.0f);
    }
  }
  if (t == 0) off[0] = 0;
}

__global__ void fill_csr(const int* __restrict__ src, const int* __restrict__ dst,
                         const int* __restrict__ off, int* __restrict__ cur,
                         int* __restrict__ csr, int e) {
  int i = blockIdx.x * 256 + threadIdx.x;
  if (i < e) {
    int d = dst[i];
    int p = atomicAdd(&cur[d], 1);
    csr[off[d] + p] = src[i];
  }
}

// ---------------- dtype conversion ----------------
__global__ void cvt_bf16(const float* __restrict__ s, short* __restrict__ d,
                         long nvalid, long ntotal) {
  long idx = ((long)blockIdx.x * 256 + threadIdx.x) * 8;
  if (idx >= ntotal) return;
  unsigned short o[8];
  if (idx < nvalid) {
    f32x4 a = *(const f32x4*)&s[idx];
    f32x4 b = *(const f32x4*)&s[idx + 4];
    o[0] = f2bf(a[0]); o[1] = f2bf(a[1]); o[2] = f2bf(a[2]); o[3] = f2bf(a[3]);
    o[4] = f2bf(b[0]); o[5] = f2bf(b[1]); o[6] = f2bf(b[2]); o[7] = f2bf(b[3]);
  } else {
    for (int j = 0; j < 8; ++j) o[j] = 0;
  }
  *(bf16x8*)&d[idx] = *(bf16x8*)o;
}

__global__ void cvt_wcat(const float* __restrict__ wl, const float* __restrict__ wr,
                         short* __restrict__ d, long half) {
  long idx = ((long)blockIdx.x * 256 + threadIdx.x) * 8;
  if (idx >= 2 * half) return;
  const float* s = (idx < half) ? (wl + idx) : (wr + (idx - half));
  f32x4 a = *(const f32x4*)s;
  f32x4 b = *(const f32x4*)(s + 4);
  unsigned short o[8];
  o[0] = f2bf(a[0]); o[1] = f2bf(a[1]); o[2] = f2bf(a[2]); o[3] = f2bf(a[3]);
  o[4] = f2bf(b[0]); o[5] = f2bf(b[1]); o[6] = f2bf(b[2]); o[7] = f2bf(b[3]);
  *(bf16x8*)&d[idx] = *(bf16x8*)o;
}

// ---------------- bf16 MFMA GEMM: C[M][Nt] = A[M][K] @ B[Nt][K]^T ----------------
// 128x128 tile, 4 waves (2x2 of 64x64), 16x16x32 MFMA, BK=64 (half the barriers
// of BK=32), global_load_lds width 16.
__global__ __launch_bounds__(256, 2) void gemm_bt(
    const short* __restrict__ A, const short* __restrict__ B,
    float* __restrict__ C, int M, int Nt, int K) {
  __shared__ short lds[2 * 128 * 64];           // A: [0,8192) shorts, B: [8192,16384)
  const int tiles_n = Nt >> 7;
  const int bm = blockIdx.x / tiles_n;
  const int bn = blockIdx.x % tiles_n;
  const int t = threadIdx.x;
  const int lane = t & 63;
  const int w = t >> 6;
  const int wr = w >> 1, wc = w & 1;
  const int lr = lane & 15, lk = lane >> 4;

  f32x4 acc[4][4] = {};

  short* ldsA = lds;
  short* ldsB = lds + 8192;

  // staging: 128 rows x 64 cols per matrix = 1024 16B-chunks; 256 threads x 4.
  // chunk c = t + j*256 -> row c>>3, col8 = c&7.
  const int srow = t >> 3, scol = (t & 7) * 8;

  for (int k0 = 0; k0 < K; k0 += 64) {
    __syncthreads();
#pragma unroll
    for (int j = 0; j < 4; ++j) {
      int c = t + j * 256;
      gload16(A + (size_t)(bm * 128 + srow + j * 32) * K + k0 + scol, ldsA + c * 8);
    }
#pragma unroll
    for (int j = 0; j < 4; ++j) {
      int c = t + j * 256;
      gload16(B + (size_t)(bn * 128 + srow + j * 32) * K + k0 + scol, ldsB + c * 8);
    }
    __syncthreads();
    bf16x8 a[4][2], b[4][2];
#pragma unroll
    for (int m = 0; m < 4; ++m)
#pragma unroll
      for (int ks = 0; ks < 2; ++ks)
        a[m][ks] = *(bf16x8*)&ldsA[(wr * 64 + m * 16 + lr) * 64 + ks * 32 + lk * 8];
#pragma unroll
    for (int n = 0; n < 4; ++n)
#pragma unroll
      for (int ks = 0; ks < 2; ++ks)
        b[n][ks] = *(bf16x8*)&ldsB[(wc * 64 + n * 16 + lr) * 64 + ks * 32 + lk * 8];
#pragma unroll
    for (int ks = 0; ks < 2; ++ks)
#pragma unroll
      for (int m = 0; m < 4; ++m)
#pragma unroll
        for (int n = 0; n < 4; ++n)
          acc[m][n] = __builtin_amdgcn_mfma_f32_16x16x32_bf16(a[m][ks], b[n][ks], acc[m][n], 0, 0, 0);
  }

  const int crow0 = bm * 128 + wr * 64 + lk * 4;   // C/D: col=lane&15, row=(lane>>4)*4+j
  const int ccol0 = bn * 128 + wc * 64 + lr;
#pragma unroll
  for (int m = 0; m < 4; ++m)
#pragma unroll
    for (int n = 0; n < 4; ++n)
#pragma unroll
      for (int j = 0; j < 4; ++j)
        C[(size_t)(crow0 + m * 16 + j) * Nt + ccol0 + n * 16] = acc[m][n][j];
}

// ---------------- fused CSR mean-aggregate + combine ----------------
// out_i = relu( mean_j Y[j][0:512] + b + Y[i][512:1024] ), write bf16 and/or f32.
__global__ __launch_bounds__(128) void agg_combine(
    const float* __restrict__ Y, const int* __restrict__ off, const int* __restrict__ csr,
    const float* __restrict__ inv_deg, const float* __restrict__ bias,
    short* __restrict__ hb, float* __restrict__ hf) {
  int i = blockIdx.x;
  int t = threadIdx.x;             // one float4 of the 512 agg cols
  int e0 = off[i], e1 = off[i + 1];
  f32x4 s = {0.f, 0.f, 0.f, 0.f};
  for (int e = e0; e < e1; ++e) {
    int sn = csr[e];
    s += ((const f32x4*)Y)[(size_t)sn * 256 + t];   // row stride 1024 f32
  }
  float id = inv_deg[i];
  f32x4 z = ((const f32x4*)Y)[(size_t)i * 256 + 128 + t];  // cols 512..1023
  f32x4 b = ((const f32x4*)bias)[t];
  f32x4 r;
#pragma unroll
  for (int j = 0; j < 4; ++j) r[j] = fmaxf(s[j] * id + b[j] + z[j], 0.f);
  if (hf) ((f32x4*)hf)[(size_t)i * 128 + t] = r;
  if (hb) {
    unsigned short o[4] = {f2bf(r[0]), f2bf(r[1]), f2bf(r[2]), f2bf(r[3])};
    *(uint2*)&hb[(size_t)i * 512 + t * 4] = *(uint2*)o;
  }
}

// ---------------- layer 3: [N,512] f32 @ [12,512]^T -> y3z3 [N][12] ----------------
__global__ __launch_bounds__(256) void l3_gemm(const float* __restrict__ h2,
                                               const float* __restrict__ w3l,
                                               const float* __restrict__ w3r,
                                               float* __restrict__ y3z3, int n) {
  __shared__ float wsh[12 * 512];
  int t = threadIdx.x;
  for (int idx = t; idx < 12 * 512; idx += 256) {
    int r = idx >> 9, c = idx & 511;
    wsh[idx] = (r < 6) ? w3l[r * 512 + c] : w3r[(r - 6) * 512 + c];
  }
  __syncthreads();
  int wid = t >> 6, lane = t & 63;
  int row = blockIdx.x * 4 + wid;
  if (row >= n) return;
  const f32x4* h4 = (const f32x4*)(h2 + (size_t)row * 512);
  f32x4 ha = h4[lane * 2], hb = h4[lane * 2 + 1];
#pragma unroll
  for (int c = 0; c < 12; ++c) {
    const f32x4* w4 = (const f32x4*)&wsh[c * 512];
    f32x4 wa = w4[lane * 2], wb = w4[lane * 2 + 1];
    float s = ha[0] * wa[0] + ha[1] * wa[1] + ha[2] * wa[2] + ha[3] * wa[3]
            + hb[0] * wb[0] + hb[1] * wb[1] + hb[2] * wb[2] + hb[3] * wb[3];
#pragma unroll
    for (int o = 32; o; o >>= 1) s += __shfl_down(s, o, 64);
    if (lane == 0) y3z3[(size_t)row * 12 + c] = s;
  }
}

__global__ void final_out(const float* __restrict__ y3z3, const int* __restrict__ off,
                          const int* __restrict__ csr, const float* __restrict__ inv_deg,
                          const float* __restrict__ b3, float* __restrict__ out, int n) {
  int idx = blockIdx.x * 256 + threadIdx.x;
  if (idx >= n * 6) return;
  int i = idx / 6, c = idx - i * 6;
  float s = 0.f;
  int e0 = off[i], e1 = off[i + 1];
  for (int e = e0; e < e1; ++e) s += y3z3[(size_t)csr[e] * 12 + c];
  out[idx] = s * inv_deg[i] + b3[c] + y3z3[(size_t)i * 12 + 6 + c];
}

// ---------------- host ----------------
extern "C" void kernel_launch(void* const* d_in, const int* in_sizes, int n_in,
                              void* d_out, int out_size, void* d_ws, size_t ws_size,
                              hipStream_t stream) {
  const float* x   = (const float*)d_in[0];
  const int*   ei  = (const int*)d_in[1];
  const float* W1l = (const float*)d_in[2];
  const float* b1  = (const float*)d_in[3];
  const float* W1r = (const float*)d_in[4];
  const float* W2l = (const float*)d_in[5];
  const float* b2  = (const float*)d_in[6];
  const float* W2r = (const float*)d_in[7];
  const float* W3l = (const float*)d_in[8];
  const float* b3  = (const float*)d_in[9];
  const float* W3r = (const float*)d_in[10];
  const int* src = ei;
  const int* dst = ei + N_EDGES;

  char* p = (char*)d_ws;
  auto alloc = [&](size_t bytes) { char* r = p; p += (bytes + 255) & ~(size_t)255; return r; };
  int*   deg     = (int*)alloc((size_t)N_NODES * 4);
  int*   off     = (int*)alloc((size_t)(N_NODES + 1) * 4);
  int*   cur     = (int*)alloc((size_t)N_NODES * 4);
  int*   csr     = (int*)alloc((size_t)N_EDGES * 4);
  float* inv_deg = (float*)alloc((size_t)N_NODES * 4);
  short* xb      = (short*)alloc((size_t)MP * F_DIM * 2);
  short* Wc      = (short*)alloc((size_t)1024 * F_DIM * 2);
  float* Cbuf    = (float*)alloc((size_t)MP * 1024 * 4);
  short* hbuf    = (short*)alloc((size_t)MP * 512 * 2);
  float* y3z3    = (float*)alloc((size_t)N_NODES * 12 * 4);

  float* h_out   = (float*)d_out;                          // [N][512]
  float* o_out   = (float*)d_out + (size_t)N_NODES * 512;  // [N][6]

  // CSR build
  hipMemsetAsync(deg, 0, (size_t)N_NODES * 4, stream);
  hipMemsetAsync(cur, 0, (size_t)N_NODES * 4, stream);
  count_deg<<<(N_EDGES + 255) / 256, 256, 0, stream>>>(dst, deg, N_EDGES);
  scan_deg<<<1, 1024, 0, stream>>>(deg, off, inv_deg, N_NODES);
  fill_csr<<<(N_EDGES + 255) / 256, 256, 0, stream>>>(src, dst, off, cur, csr, N_EDGES);

  // x -> bf16 (padded rows zeroed)
  {
    long ntotal = (long)MP * F_DIM;
    cvt_bf16<<<(int)((ntotal / 8 + 255) / 256), 256, 0, stream>>>(
        x, xb, (long)N_NODES * F_DIM, ntotal);
  }

  // ---- layer 1 ----
  cvt_wcat<<<(int)(((long)1024 * F_DIM / 8 + 255) / 256), 256, 0, stream>>>(
      W1l, W1r, Wc, (long)512 * F_DIM);
  gemm_bt<<<(MP / 128) * (1024 / 128), 256, 0, stream>>>(xb, Wc, Cbuf, MP, 1024, F_DIM);
  agg_combine<<<N_NODES, 128, 0, stream>>>(Cbuf, off, csr, inv_deg, b1, hbuf, nullptr);

  // ---- layer 2 ----
  cvt_wcat<<<(int)(((long)1024 * 512 / 8 + 255) / 256), 256, 0, stream>>>(
      W2l, W2r, Wc, (long)512 * 512);
  gemm_bt<<<(MP / 128) * (1024 / 128), 256, 0, stream>>>(hbuf, Wc, Cbuf, MP, 1024, 512);
  agg_combine<<<N_NODES, 128, 0, stream>>>(Cbuf, off, csr, inv_deg, b2, nullptr, h_out);

  // ---- layer 3 ----
  l3_gemm<<<(N_NODES + 3) / 4, 256, 0, stream>>>(h_out, W3l, W3r, y3z3, N_NODES);
  final_out<<<(N_NODES * 6 + 255) / 256, 256, 0, stream>>>(y3z3, off, csr, inv_deg, b3, o_out, N_NODES);
}